// Round 4
// baseline (286.690 us; speedup 1.0000x reference)
//
#include <hip/hip_runtime.h>
#include <math.h>

#define B 1024
#define T 512
#define S 48
#define SOS 47

// broadcast lane 1's value to all lanes
__device__ __forceinline__ float rdlane1(float v) {
    return __int_as_float(__builtin_amdgcn_readlane(__float_as_int(v), 1));
}

// ---------------------------------------------------------------------------
// Fused CRF loss. One wave per row; lane i owns state i; expT row in VGPRs.
// Scan kept in exp space with DELAYED normalization:
//   invariant  true_score_i = log(q_i) + M   (r_s == exp(-l_s) pending)
//   live step: q' = (expT q) * exp(emis - er) * r_s ;  M += er + l_s
//              then r_s = rcp(d1), l_s = log(d1)   [off critical chain]
// Critical chain/step: ds_read(bcast) -> FMA dot -> mul -> select -> ds_write.
// Mask is consumed as a 512-bit LDS bitmap (built via __ballot in the
// numerator pass): no per-step mask vmem, no mring registers.
// amdgpu_waves_per_eu(1,1): min=max=1 wave/EU pins the VGPR budget at 512
// (single-arg form only sets the min; allocator kept capping at 64 = 512/8).
// Occupancy is structurally 1 wave/SIMD (1024 waves on 1024 SIMDs) anyway.
// ---------------------------------------------------------------------------
__global__ __launch_bounds__(64)
__attribute__((amdgpu_waves_per_eu(1, 1)))
void crf_fused(const float* __restrict__ feat,
               const int* __restrict__ states,
               const float* __restrict__ mask,
               const float* __restrict__ trans,
               float* __restrict__ out) {
    __shared__ __align__(16) float pbuf[2][64];
    __shared__ unsigned long long mbits[T / 64];    // 512-bit mask bitmap
    const int b = blockIdx.x;
    const int lane = threadIdx.x;
    const int elane = (lane < S) ? lane : 0;        // lanes 48-63 shadow lane 0
    const float* f_b = feat + (size_t)b * T * S;
    const float* m_b = mask + b * T;
    const int* st_b = states + b * T;

    // ---- numerator + mask-bitmap build (latency overlaps expT setup) ----
    float nsum = 0.f;
#pragma unroll
    for (int k2 = 0; k2 < T / 64; ++k2) {
        const int t = lane + k2 * 64;
        const int st = st_b[t];
        const int pv = (t == 0) ? SOS : st_b[t - 1];
        const float m = m_b[t];
        nsum += (f_b[t * S + st] + trans[st * S + pv]) * m;
        const unsigned long long bal = __ballot(m != 0.f);
        if (lane == 0) mbits[k2] = bal;
    }

    // ---- expT row for this lane; exp(-9999) underflows to exact 0 ----
    float expT[S];
    {
        const float4* t4 = (const float4*)(trans + elane * S);
#pragma unroll
        for (int j4 = 0; j4 < S / 4; ++j4) {
            const float4 tv = t4[j4];
            expT[4 * j4 + 0] = (lane < S) ? __expf(tv.x) : 0.f;
            expT[4 * j4 + 1] = (lane < S) ? __expf(tv.y) : 0.f;
            expT[4 * j4 + 2] = (lane < S) ? __expf(tv.z) : 0.f;
            expT[4 * j4 + 3] = (lane < S) ? __expf(tv.w) : 0.f;
        }
    }

    // ---- scan state ----
    float q = (lane == SOS) ? 1.f : 0.f;
    float M = 0.f;
    float r_s = 1.f, l_s = 0.f;       // pending normalizer: r_s == exp(-l_s)
    pbuf[0][lane] = q;

    // emission prefetch, double-buffered 8-step blocks (~1700 cyc of age)
    float ering[2][8];
#pragma unroll
    for (int k = 0; k < 8; ++k)
        ering[0][k] = f_b[k * S + elane];

#pragma unroll 2
    for (int tb = 0; tb < T / 8; ++tb) {
        const int pb = tb & 1;
        // issue next block's emission loads now; consumed a full block later
        const int tn = ((tb + 1) & (T / 8 - 1)) * 8;   // wrap: last refill unused
#pragma unroll
        for (int k = 0; k < 8; ++k)
            ering[pb ^ 1][k] = f_b[(tn + k) * S + elane];
        // this block's 8 mask bits (uniform; volatile so it can't be hoisted)
        const unsigned int mbyte =
            ((const volatile unsigned char*)mbits)[tb];
#pragma unroll
        for (int k = 0; k < 8; ++k) {
            // off-chain: per-lane factor from prefetched emission
            const float emis = ering[pb][k];
            const float er = rdlane1(emis);
            const float F = __expf(emis - er) * r_s;
            // chain: broadcast dot d_i = expT[i] . q
            const float4* qb = (const float4*)pbuf[k & 1];
            float ax = 0.f, ay = 0.f, az = 0.f, aw = 0.f;
#pragma unroll
            for (int j4 = 0; j4 < S / 4; ++j4) {
                const float4 pv4 = qb[j4];      // same-address LDS broadcast
                ax = fmaf(expT[4 * j4 + 0], pv4.x, ax);
                ay = fmaf(expT[4 * j4 + 1], pv4.y, ay);
                az = fmaf(expT[4 * j4 + 2], pv4.z, az);
                aw = fmaf(expT[4 * j4 + 3], pv4.w, aw);
            }
            const float d = (ax + ay) + (az + aw);
            const float qn = d * F;
            const bool live = ((mbyte >> k) & 1u) != 0u;
            q = live ? qn : q;                  // SELECT, never blend
            pbuf[(k + 1) & 1][lane] = q;
            // off-chain: next normalizer + shift bookkeeping
            M = live ? (M + er + l_s) : M;      // uses OLD l_s, then update
            const float dr = rdlane1(d);        // lane1 dot: provably > 0
            const float nl = __logf(dr);
            const float nr = __builtin_amdgcn_rcpf(dr);
            r_s = live ? nr : r_s;
            l_s = live ? nl : l_s;
        }
    }

    // ---- epilogue: denom = M + log(sum_i q_i); out = denom - numer ----
    float ps = q;                               // lanes >= 48 hold 0
#pragma unroll
    for (int off = 32; off > 0; off >>= 1) {
        ps += __shfl_xor(ps, off, 64);
        nsum += __shfl_xor(nsum, off, 64);
    }
    if (lane == 0) out[b] = M + __logf(ps) - nsum;
}

extern "C" void kernel_launch(void* const* d_in, const int* in_sizes, int n_in,
                              void* d_out, int out_size, void* d_ws, size_t ws_size,
                              hipStream_t stream) {
    const float* feat   = (const float*)d_in[0];   // (B,T,S) f32
    const int*   states = (const int*)d_in[1];     // (B,T) i32
    const float* mask   = (const float*)d_in[2];   // (B,T) f32
    const float* trans  = (const float*)d_in[3];   // (S,S) f32
    float* out = (float*)d_out;                    // (B,) f32

    crf_fused<<<dim3(B), dim3(64), 0, stream>>>(feat, states, mask, trans, out);
}